// Round 5
// baseline (175.805 us; speedup 1.0000x reference)
//
#include <hip/hip_runtime.h>

// HybridLoss: 0.8*MSE + 0.2*(1-SSIM), SSIM via separable 11x11 Gaussian (sigma=1.5)
// Input: pred, target f32 (32,3,512,512). Output: scalar f32.
// Streaming strip (64 wide x 128 tall), 16-row chunks through a 26-row circular
// LDS buffer holding ONE float4/px: (mu_x, mu_y, E[x^2+y^2], E[xy]).
// sigma_x2+sigma_y2 = E[x^2+y^2] - mu_x^2 - mu_y^2 recovers the SSIM denominator.

#define W 512
#define H 512
#define NIMG 96
#define TX 64
#define CHUNK 16
#define STRIP 128
#define NITER 8            // STRIP/CHUNK
#define BUF 26             // circular buffer rows (14-tap window + 12 lookahead)
#define PAD4 65            // float4 row stride: 1040 B == 16 mod 128 -> conflict-free
#define NSLOT 128

__global__ void hybrid_init(double* __restrict__ ws) {
    int t = threadIdx.x;
    if (t < 2 * NSLOT) ws[t] = 0.0;
}

__global__ __launch_bounds__(256, 6) void hybrid_main(
    const float* __restrict__ pred, const float* __restrict__ targ,
    double* __restrict__ ws)
{
    __shared__ float4 s_q[BUF][PAD4];   // 26*1040 = 27040 B -> 6 blocks/CU

    const int tid = threadIdx.x;
    const float* __restrict__ pp = pred + (size_t)blockIdx.z * (H * W);
    const float* __restrict__ tp = targ + (size_t)blockIdx.z * (H * W);
    const int xbase = blockIdx.x * TX;
    const int Y0 = blockIdx.y * STRIP;

    // Normalized 1D Gaussian (separable form of outer(g,g)/sum), f32 like ref
    float gw[11];
    {
        float s = 0.f;
#pragma unroll
        for (int k = 0; k < 11; ++k) {
            float d = (float)(k - 5);
            gw[k] = expf(-d * d / 4.5f);   // 2*sigma^2 = 4.5
            s += gw[k];
        }
        float inv = 1.f / s;
#pragma unroll
        for (int k = 0; k < 11; ++k) gw[k] *= inv;
    }

    const int hrow_i = tid >> 4;       // 0..15 : hconv row-in-chunk
    const int g      = tid & 15;       // 4-col group
    const int c0     = g * 4;
    const int A0     = xbase + c0 - 8; // aligned 20-px window [A0, A0+20)
    const bool inX   = (A0 >= 0) && (A0 + 20 <= W);

    const int wv = tid >> 6;           // wave 0..3 (vconv 4-row runs)
    const int cc = tid & 63;           // output column within tile

    float mse_local = 0.f, ssim_local = 0.f;

    // hconv one image row (gy) into circular slot; MSE on raw pred if owned.
    auto hconv_row = [&](int gy, int slot, bool own) {
        float xa[20], ya[20];
        if (gy >= 0 && gy < H) {
            const float* __restrict__ px = pp + (size_t)gy * W;
            const float* __restrict__ py = tp + (size_t)gy * W;
            if (inX) {
                const float4* qx = (const float4*)(px + A0);
                const float4* qy = (const float4*)(py + A0);
#pragma unroll
                for (int v = 0; v < 5; ++v) {
                    float4 a = qx[v], b = qy[v];
                    xa[4*v+0]=a.x; xa[4*v+1]=a.y; xa[4*v+2]=a.z; xa[4*v+3]=a.w;
                    ya[4*v+0]=b.x; ya[4*v+1]=b.y; ya[4*v+2]=b.z; ya[4*v+3]=b.w;
                }
            } else {
#pragma unroll
                for (int j = 0; j < 20; ++j) {
                    int col = A0 + j;
                    bool ok = (col >= 0) && (col < W);
                    xa[j] = ok ? px[col] : 0.f;
                    ya[j] = ok ? py[col] : 0.f;
                }
            }
        } else {
#pragma unroll
            for (int j = 0; j < 20; ++j) { xa[j] = 0.f; ya[j] = 0.f; }
        }

        float a0[4]={0,0,0,0}, a1[4]={0,0,0,0}, a2[4]={0,0,0,0}, a3[4]={0,0,0,0};
#pragma unroll
        for (int j = 0; j < 14; ++j) {        // window positions 3..16
            float xv = xa[3 + j], yv = ya[3 + j];
            if (j >= 5 && j <= 8 && own) {    // owned pixels, raw pred
                float d = xv - yv;
                mse_local = fmaf(d, d, mse_local);
            }
            float cx = fminf(fmaxf(xv, 0.f), 1.f);   // SSIM uses clipped pred
            float s2 = fmaf(yv, yv, cx * cx);        // x^2 + y^2
            float xy = cx * yv;
#pragma unroll
            for (int i = 0; i < 4; ++i) {
                int k = j - i;
                if (k >= 0 && k < 11) {
                    float w = gw[k];
                    a0[i] = fmaf(w, cx, a0[i]);
                    a1[i] = fmaf(w, yv, a1[i]);
                    a2[i] = fmaf(w, s2, a2[i]);
                    a3[i] = fmaf(w, xy, a3[i]);
                }
            }
        }
#pragma unroll
        for (int i = 0; i < 4; ++i)
            s_q[slot][c0 + i] = make_float4(a0[i], a1[i], a2[i], a3[i]);
    };

    // Prologue: ext rows 0..9 (gy = Y0-5 .. Y0+4) -> slots 0..9
    if (hrow_i < 10) {
        hconv_row(Y0 - 5 + hrow_i, hrow_i, hrow_i >= 5);
    }

    const float C1 = 1e-4f, C2 = 9e-4f;

#pragma unroll
    for (int k = 0; k < NITER; ++k) {
        const int hb = (10 + CHUNK * k) % BUF;  // compile-time
        const int vb = (CHUNK * k) % BUF;       // compile-time

        // ---- hconv-write: ext rows 16k+10 .. 16k+25 (1 task/thread) ----
        {
            int ext  = 16 * k + 10 + hrow_i;
            int slot = hb + hrow_i; if (slot >= BUF) slot -= BUF;
            hconv_row(Y0 - 5 + ext, slot, ext <= 132);
        }
        __syncthreads();

        // ---- vconv: output rows 16k + 4*wv .. +3 (1 task/thread) ----
        {
            int t0 = vb + 4 * wv; if (t0 >= BUF) t0 -= BUF;
            float ax[4]={0,0,0,0}, ay[4]={0,0,0,0};
            float as[4]={0,0,0,0}, axy[4]={0,0,0,0};
#pragma unroll
            for (int j = 0; j < 14; ++j) {
                int s = t0 + j; if (s >= BUF) s -= BUF;
                float4 q = s_q[s][cc];
#pragma unroll
                for (int i = 0; i < 4; ++i) {
                    int kk = j - i;
                    if (kk >= 0 && kk < 11) {
                        float w = gw[kk];
                        ax [i] = fmaf(w, q.x, ax [i]);
                        ay [i] = fmaf(w, q.y, ay [i]);
                        as [i] = fmaf(w, q.z, as [i]);
                        axy[i] = fmaf(w, q.w, axy[i]);
                    }
                }
            }
#pragma unroll
            for (int i = 0; i < 4; ++i) {
                float mu_x2 = ax[i]*ax[i], mu_y2 = ay[i]*ay[i], mu_xy = ax[i]*ay[i];
                float ssum = as[i] - mu_x2 - mu_y2;      // sigma_x2 + sigma_y2
                float sxy  = axy[i] - mu_xy;
                float num = (2.f*mu_xy + C1) * (2.f*sxy + C2);
                float den = (mu_x2 + mu_y2 + C1) * (ssum + C2);
                ssim_local = fmaf(num, __builtin_amdgcn_rcpf(den), ssim_local);
            }
        }
        __syncthreads();
    }

    // ---- Per-wave reduction + spread f64 atomics ----
    float m = mse_local, s2 = ssim_local;
#pragma unroll
    for (int off = 32; off; off >>= 1) {
        m  += __shfl_down(m, off);
        s2 += __shfl_down(s2, off);
    }
    if ((tid & 63) == 0) {
        int flat = blockIdx.x + 8 * (blockIdx.y + 4 * blockIdx.z);
        int slot = (flat * 4 + wv) & (NSLOT - 1);
        atomicAdd(&ws[slot], (double)m);
        atomicAdd(&ws[NSLOT + slot], (double)s2);
    }
}

__global__ void hybrid_fin(const double* __restrict__ ws, float* __restrict__ out) {
    int t = threadIdx.x;  // 64 threads
    double m = ws[t] + ws[t + 64];
    double s = ws[NSLOT + t] + ws[NSLOT + t + 64];
#pragma unroll
    for (int off = 32; off; off >>= 1) {
        m += __shfl_down(m, off);
        s += __shfl_down(s, off);
    }
    if (t == 0) {
        const double N = (double)NIMG * H * W;
        double mse  = m / N;
        double ssim = s / N;
        out[0] = (float)(0.8 * mse + 0.2 * (1.0 - ssim));
    }
}

extern "C" void kernel_launch(void* const* d_in, const int* in_sizes, int n_in,
                              void* d_out, int out_size, void* d_ws, size_t ws_size,
                              hipStream_t stream) {
    const float* pred = (const float*)d_in[0];
    const float* targ = (const float*)d_in[1];
    double* ws = (double*)d_ws;
    float* out = (float*)d_out;

    hybrid_init<<<1, 256, 0, stream>>>(ws);
    dim3 grid(W / TX, H / STRIP, NIMG);
    hybrid_main<<<grid, dim3(256), 0, stream>>>(pred, targ, ws);
    hybrid_fin<<<1, 64, 0, stream>>>(ws, out);
}

// Round 6
// 122.443 us; speedup vs baseline: 1.4358x; 1.4358x over previous
//
#include <hip/hip_runtime.h>

// HybridLoss: 0.8*MSE + 0.2*(1-SSIM), SSIM via separable 11x11 Gaussian (sigma=1.5)
// Input: pred, target f32 (32,3,512,512). Output: scalar f32.
// Streaming strip (64 wide x 128 tall), 16-row chunks through a 26-row circular
// LDS buffer holding ONE float4/px: (mu_x, mu_y, E[x^2+y^2], E[xy]).
// sigma_x2+sigma_y2 = E[x^2+y^2] - mu_x^2 - mu_y^2 recovers the SSIM denominator.
// launch_bounds(256,4): (256,6) forced VGPR->40 and spilled xa/ya to scratch
// (80 MB scratch writes/dispatch, VALUBusy 63->40%). Keep regalloc headroom.

#define W 512
#define H 512
#define NIMG 96
#define TX 64
#define CHUNK 16
#define STRIP 128
#define NITER 8            // STRIP/CHUNK
#define BUF 26             // circular buffer rows (14-tap window + 12 lookahead)
#define PAD4 65            // float4 row stride: 1040 B == 16 mod 128 -> uniform bank spread
#define NSLOT 128

__global__ void hybrid_init(double* __restrict__ ws) {
    int t = threadIdx.x;
    if (t < 2 * NSLOT) ws[t] = 0.0;
}

__global__ __launch_bounds__(256, 4) void hybrid_main(
    const float* __restrict__ pred, const float* __restrict__ targ,
    double* __restrict__ ws)
{
    __shared__ float4 s_q[BUF][PAD4];   // 26*1040 = 27040 B -> 5 blocks/CU (LDS-limited)

    const int tid = threadIdx.x;
    const float* __restrict__ pp = pred + (size_t)blockIdx.z * (H * W);
    const float* __restrict__ tp = targ + (size_t)blockIdx.z * (H * W);
    const int xbase = blockIdx.x * TX;
    const int Y0 = blockIdx.y * STRIP;

    // Normalized 1D Gaussian (separable form of outer(g,g)/sum), f32 like ref
    float gw[11];
    {
        float s = 0.f;
#pragma unroll
        for (int k = 0; k < 11; ++k) {
            float d = (float)(k - 5);
            gw[k] = expf(-d * d / 4.5f);   // 2*sigma^2 = 4.5
            s += gw[k];
        }
        float inv = 1.f / s;
#pragma unroll
        for (int k = 0; k < 11; ++k) gw[k] *= inv;
    }

    const int hrow_i = tid >> 4;       // 0..15 : hconv row-in-chunk
    const int g      = tid & 15;       // 4-col group
    const int c0     = g * 4;
    const int A0     = xbase + c0 - 8; // aligned 20-px window [A0, A0+20)
    const bool inX   = (A0 >= 0) && (A0 + 20 <= W);

    const int wv = tid >> 6;           // wave 0..3 (vconv 4-row runs)
    const int cc = tid & 63;           // output column within tile

    float mse_local = 0.f, ssim_local = 0.f;

    // hconv one image row (gy) into circular slot; MSE on raw pred if owned.
    auto hconv_row = [&](int gy, int slot, bool own) {
        float xa[20], ya[20];
        if (gy >= 0 && gy < H) {
            const float* __restrict__ px = pp + (size_t)gy * W;
            const float* __restrict__ py = tp + (size_t)gy * W;
            if (inX) {
                const float4* qx = (const float4*)(px + A0);
                const float4* qy = (const float4*)(py + A0);
#pragma unroll
                for (int v = 0; v < 5; ++v) {
                    float4 a = qx[v], b = qy[v];
                    xa[4*v+0]=a.x; xa[4*v+1]=a.y; xa[4*v+2]=a.z; xa[4*v+3]=a.w;
                    ya[4*v+0]=b.x; ya[4*v+1]=b.y; ya[4*v+2]=b.z; ya[4*v+3]=b.w;
                }
            } else {
#pragma unroll
                for (int j = 0; j < 20; ++j) {
                    int col = A0 + j;
                    bool ok = (col >= 0) && (col < W);
                    xa[j] = ok ? px[col] : 0.f;
                    ya[j] = ok ? py[col] : 0.f;
                }
            }
        } else {
#pragma unroll
            for (int j = 0; j < 20; ++j) { xa[j] = 0.f; ya[j] = 0.f; }
        }

        float a0[4]={0,0,0,0}, a1[4]={0,0,0,0}, a2[4]={0,0,0,0}, a3[4]={0,0,0,0};
#pragma unroll
        for (int j = 0; j < 14; ++j) {        // window positions 3..16
            float xv = xa[3 + j], yv = ya[3 + j];
            if (j >= 5 && j <= 8 && own) {    // owned pixels, raw pred
                float d = xv - yv;
                mse_local = fmaf(d, d, mse_local);
            }
            float cx = fminf(fmaxf(xv, 0.f), 1.f);   // SSIM uses clipped pred
            float s2 = fmaf(yv, yv, cx * cx);        // x^2 + y^2
            float xy = cx * yv;
#pragma unroll
            for (int i = 0; i < 4; ++i) {
                int k = j - i;
                if (k >= 0 && k < 11) {
                    float w = gw[k];
                    a0[i] = fmaf(w, cx, a0[i]);
                    a1[i] = fmaf(w, yv, a1[i]);
                    a2[i] = fmaf(w, s2, a2[i]);
                    a3[i] = fmaf(w, xy, a3[i]);
                }
            }
        }
#pragma unroll
        for (int i = 0; i < 4; ++i)
            s_q[slot][c0 + i] = make_float4(a0[i], a1[i], a2[i], a3[i]);
    };

    // Prologue: ext rows 0..9 (gy = Y0-5 .. Y0+4) -> slots 0..9
    if (hrow_i < 10) {
        hconv_row(Y0 - 5 + hrow_i, hrow_i, hrow_i >= 5);
    }

    const float C1 = 1e-4f, C2 = 9e-4f;

#pragma unroll
    for (int k = 0; k < NITER; ++k) {
        const int hb = (10 + CHUNK * k) % BUF;  // compile-time
        const int vb = (CHUNK * k) % BUF;       // compile-time

        // ---- hconv-write: ext rows 16k+10 .. 16k+25 (1 task/thread) ----
        {
            int ext  = 16 * k + 10 + hrow_i;
            int slot = hb + hrow_i; if (slot >= BUF) slot -= BUF;
            hconv_row(Y0 - 5 + ext, slot, ext <= 132);
        }
        __syncthreads();

        // ---- vconv: output rows 16k + 4*wv .. +3 (1 task/thread) ----
        {
            int t0 = vb + 4 * wv; if (t0 >= BUF) t0 -= BUF;
            float ax[4]={0,0,0,0}, ay[4]={0,0,0,0};
            float as[4]={0,0,0,0}, axy[4]={0,0,0,0};
#pragma unroll
            for (int j = 0; j < 14; ++j) {
                int s = t0 + j; if (s >= BUF) s -= BUF;
                float4 q = s_q[s][cc];
#pragma unroll
                for (int i = 0; i < 4; ++i) {
                    int kk = j - i;
                    if (kk >= 0 && kk < 11) {
                        float w = gw[kk];
                        ax [i] = fmaf(w, q.x, ax [i]);
                        ay [i] = fmaf(w, q.y, ay [i]);
                        as [i] = fmaf(w, q.z, as [i]);
                        axy[i] = fmaf(w, q.w, axy[i]);
                    }
                }
            }
#pragma unroll
            for (int i = 0; i < 4; ++i) {
                float mu_x2 = ax[i]*ax[i], mu_y2 = ay[i]*ay[i], mu_xy = ax[i]*ay[i];
                float ssum = as[i] - mu_x2 - mu_y2;      // sigma_x2 + sigma_y2
                float sxy  = axy[i] - mu_xy;
                float num = (2.f*mu_xy + C1) * (2.f*sxy + C2);
                float den = (mu_x2 + mu_y2 + C1) * (ssum + C2);
                ssim_local = fmaf(num, __builtin_amdgcn_rcpf(den), ssim_local);
            }
        }
        __syncthreads();
    }

    // ---- Per-wave reduction + spread f64 atomics ----
    float m = mse_local, s2 = ssim_local;
#pragma unroll
    for (int off = 32; off; off >>= 1) {
        m  += __shfl_down(m, off);
        s2 += __shfl_down(s2, off);
    }
    if ((tid & 63) == 0) {
        int flat = blockIdx.x + 8 * (blockIdx.y + 4 * blockIdx.z);
        int slot = (flat * 4 + wv) & (NSLOT - 1);
        atomicAdd(&ws[slot], (double)m);
        atomicAdd(&ws[NSLOT + slot], (double)s2);
    }
}

__global__ void hybrid_fin(const double* __restrict__ ws, float* __restrict__ out) {
    int t = threadIdx.x;  // 64 threads
    double m = ws[t] + ws[t + 64];
    double s = ws[NSLOT + t] + ws[NSLOT + t + 64];
#pragma unroll
    for (int off = 32; off; off >>= 1) {
        m += __shfl_down(m, off);
        s += __shfl_down(s, off);
    }
    if (t == 0) {
        const double N = (double)NIMG * H * W;
        double mse  = m / N;
        double ssim = s / N;
        out[0] = (float)(0.8 * mse + 0.2 * (1.0 - ssim));
    }
}

extern "C" void kernel_launch(void* const* d_in, const int* in_sizes, int n_in,
                              void* d_out, int out_size, void* d_ws, size_t ws_size,
                              hipStream_t stream) {
    const float* pred = (const float*)d_in[0];
    const float* targ = (const float*)d_in[1];
    double* ws = (double*)d_ws;
    float* out = (float*)d_out;

    hybrid_init<<<1, 256, 0, stream>>>(ws);
    dim3 grid(W / TX, H / STRIP, NIMG);
    hybrid_main<<<grid, dim3(256), 0, stream>>>(pred, targ, ws);
    hybrid_fin<<<1, 64, 0, stream>>>(ws, out);
}